// Round 8
// baseline (334.730 us; speedup 1.0000x reference)
//
#include <hip/hip_runtime.h>
#include <hip/hip_bf16.h>
#include <math.h>

#define N_NODES 100000
#define M_EDGES 800000
#define HID 128
#define HEADS 8
#define DH 16
#define SCAN_NB ((N_NODES + 1023) / 1024)   // 98 blocks of 1024 counts

typedef __attribute__((ext_vector_type(8))) short short8;   // 8 x bf16 (4 VGPRs)
typedef __attribute__((ext_vector_type(4))) float floatx4;  // MFMA accumulator

__device__ __forceinline__ ushort f32_to_bf16(float x) {
    __hip_bfloat16 h = __float2bfloat16(x);   // RNE
    union { __hip_bfloat16 h; ushort u; } c; c.h = h;
    return c.u;
}
__device__ __forceinline__ float bf16_bits_to_f32(ushort u) {
    union { unsigned int i; float f; } c; c.i = ((unsigned int)u) << 16;
    return c.f;
}
__device__ __forceinline__ float bf16pair_lo(unsigned int p) {
    union { unsigned int i; float f; } c; c.i = p << 16; return c.f;
}
__device__ __forceinline__ float bf16pair_hi(unsigned int p) {
    union { unsigned int i; float f; } c; c.i = p & 0xffff0000u; return c.f;
}

// ---------------------------------------------------------------------------
// Stage a 128x128 fp32 weight matrix into LDS as bf16 in MFMA B-fragment
// order (fragment f = ks*8+t at lds[f*512..], 64 lanes x 8 ushorts).
// Converts fp32->bf16 in-flight: no separate conversion pass needed.
// ---------------------------------------------------------------------------
__device__ __forceinline__ void stage_w_frag_f32(const float* __restrict__ W,
                                                 ushort* __restrict__ lds, int tid)
{
    #pragma unroll
    for (int i = 0; i < 8; ++i) {
        int idx  = i * 256 + tid;       // 0..2047 chunks of 8 values
        int f    = idx >> 6;
        int lane = idx & 63;
        int t    = f & 7, ks = f >> 3;
        int row  = t * 16 + (lane & 15);
        int col  = ks * 32 + (lane >> 4) * 8;
        const float* src = W + row * HID + col;
        float4 a = *(const float4*)src;
        float4 b = *(const float4*)(src + 4);
        ushort4 lo, hi;
        lo.x = f32_to_bf16(a.x); lo.y = f32_to_bf16(a.y);
        lo.z = f32_to_bf16(a.z); lo.w = f32_to_bf16(a.w);
        hi.x = f32_to_bf16(b.x); hi.y = f32_to_bf16(b.y);
        hi.z = f32_to_bf16(b.z); hi.w = f32_to_bf16(b.w);
        *(ushort4*)(lds + idx * 8)     = lo;
        *(ushort4*)(lds + idx * 8 + 4) = hi;
    }
}

// ---------------------------------------------------------------------------
// Q/K/V projection via bf16 MFMA, LDS-staged weights (fp32 src), 128 rows/blk.
// Also zeroes `count` for the downstream histogram (saves a memset dispatch;
// hist runs strictly after this kernel in stream order).
// q and v interleave into qv (node stride 256: q | v); k separate [N][128].
// ---------------------------------------------------------------------------
__global__ __launch_bounds__(256) void qkv_mfma_kernel(
    const float* __restrict__ feats,
    const float* __restrict__ Wq, const float* __restrict__ Wk, const float* __restrict__ Wv,
    ushort* __restrict__ qv16, ushort* __restrict__ k16, int* __restrict__ count)
{
    __shared__ ushort wlds[16384];                 // 32 KB, one W at a time
    const int tid  = threadIdx.x;
    const int wave = tid >> 6;
    const int lane = tid & 63;
    const int row0 = blockIdx.x * 128 + wave * 32;
    const int lrow = lane & 15;
    const int lk   = (lane >> 4) * 8;
    const int crow = (lane >> 4) * 4;

    // zero the histogram buffer (grid covers 200k threads >= N_NODES)
    int z = blockIdx.x * 256 + tid;
    if (z < N_NODES) count[z] = 0;

    // A fragments for 2 tiles x 4 ks, converted fp32->bf16 in-reg (N%16==0).
    short8 afrag[2][4];
    bool tvalid[2];
    #pragma unroll
    for (int r = 0; r < 2; ++r) {
        int rr = row0 + r * 16;
        tvalid[r] = (rr < N_NODES);
        const float* arow = feats + (size_t)((tvalid[r] ? rr : 0) + lrow) * HID + lk;
        #pragma unroll
        for (int ks = 0; ks < 4; ++ks) {
            float4 f0 = *(const float4*)(arow + ks * 32);
            float4 f1 = *(const float4*)(arow + ks * 32 + 4);
            short8 a;
            a[0] = (short)f32_to_bf16(f0.x); a[1] = (short)f32_to_bf16(f0.y);
            a[2] = (short)f32_to_bf16(f0.z); a[3] = (short)f32_to_bf16(f0.w);
            a[4] = (short)f32_to_bf16(f1.x); a[5] = (short)f32_to_bf16(f1.y);
            a[6] = (short)f32_to_bf16(f1.z); a[7] = (short)f32_to_bf16(f1.w);
            afrag[r][ks] = a;
        }
    }

    const float* Ws[3] = {Wq, Wk, Wv};
    ushort* Ob[3]; int Ostride[3];
    Ob[0] = qv16;       Ostride[0] = 256;
    Ob[1] = k16;        Ostride[1] = 128;
    Ob[2] = qv16 + 128; Ostride[2] = 256;

    #pragma unroll
    for (int w = 0; w < 3; ++w) {
        __syncthreads();                           // prior reads of wlds done
        stage_w_frag_f32(Ws[w], wlds, tid);
        __syncthreads();

        floatx4 acc[2][8];
        #pragma unroll
        for (int r = 0; r < 2; ++r)
            #pragma unroll
            for (int t = 0; t < 8; ++t) acc[r][t] = (floatx4)(0.f);

        #pragma unroll
        for (int ks = 0; ks < 4; ++ks) {
            short8 B[8];
            #pragma unroll
            for (int t = 0; t < 8; ++t)
                B[t] = *(const short8*)&wlds[(ks * 8 + t) * 512 + lane * 8];
            #pragma unroll
            for (int t = 0; t < 8; ++t) {
                acc[0][t] = __builtin_amdgcn_mfma_f32_16x16x32_bf16(B[t], afrag[0][ks], acc[0][t], 0, 0, 0);
                acc[1][t] = __builtin_amdgcn_mfma_f32_16x16x32_bf16(B[t], afrag[1][ks], acc[1][t], 0, 0, 0);
            }
        }

        #pragma unroll
        for (int r = 0; r < 2; ++r) {
            if (tvalid[r]) {
                ushort* O = Ob[w] + (size_t)(row0 + r * 16 + lrow) * Ostride[w];
                #pragma unroll
                for (int t = 0; t < 8; ++t) {
                    ushort4 o;
                    o.x = f32_to_bf16(acc[r][t][0]); o.y = f32_to_bf16(acc[r][t][1]);
                    o.z = f32_to_bf16(acc[r][t][2]); o.w = f32_to_bf16(acc[r][t][3]);
                    *(ushort4*)(O + t * 16 + crow) = o;
                }
            }
        }
    }
}

// ---------------------------------------------------------------------------
// CSR build with 4-PADDED segments: each node's segment is rounded up to a
// multiple of 4 ints so the aggregate can do aligned int4 index loads.
// hist -> blocksum(padded) -> write(local top-scan, padded) -> fill.
// ---------------------------------------------------------------------------
__global__ __launch_bounds__(256) void hist_kernel(
    const int* __restrict__ idx_ji, int* __restrict__ count)
{
    int m = blockIdx.x * 256 + threadIdx.x;
    if (m < M_EDGES) atomicAdd(&count[idx_ji[m]], 1);
}

__global__ __launch_bounds__(256) void scan_blocksum_kernel(
    const int* __restrict__ count, int* __restrict__ blocksum)
{
    __shared__ int s[256];
    const int tid = threadIdx.x;
    const int base = blockIdx.x * 1024 + tid * 4;
    int sum = 0;
    if (base + 3 < N_NODES) {
        int4 c = *(const int4*)(count + base);
        sum = ((c.x + 3) & ~3) + ((c.y + 3) & ~3) + ((c.z + 3) & ~3) + ((c.w + 3) & ~3);
    } else {
        #pragma unroll
        for (int j = 0; j < 4; ++j)
            if (base + j < N_NODES) sum += (count[base + j] + 3) & ~3;
    }
    s[tid] = sum;
    __syncthreads();
    for (int off = 128; off > 0; off >>= 1) {
        if (tid < off) s[tid] += s[tid + off];
        __syncthreads();
    }
    if (tid == 0) blocksum[blockIdx.x] = s[0];
}

__global__ __launch_bounds__(256) void scan_write_kernel(
    const int* __restrict__ count, const int* __restrict__ blocksum,
    int* __restrict__ offsets, int* __restrict__ cursor)
{
    __shared__ int s[256];
    __shared__ int bs[128];
    const int tid = threadIdx.x;

    // local inclusive scan of the 98 block sums (every block does this; cheap)
    if (tid < 128) bs[tid] = (tid < SCAN_NB) ? blocksum[tid] : 0;
    __syncthreads();
    for (int off = 1; off < 128; off <<= 1) {
        int x = (tid >= off && tid < 128) ? bs[tid - off] : 0;
        __syncthreads();
        if (tid < 128) bs[tid] += x;
        __syncthreads();
    }
    const int blockbase = (blockIdx.x == 0) ? 0 : bs[blockIdx.x - 1];

    const int base = blockIdx.x * 1024 + tid * 4;
    int c0 = 0, c1 = 0, c2 = 0, c3 = 0;
    if (base + 3 < N_NODES) {
        int4 c = *(const int4*)(count + base);
        c0 = (c.x + 3) & ~3; c1 = (c.y + 3) & ~3; c2 = (c.z + 3) & ~3; c3 = (c.w + 3) & ~3;
    } else {
        if (base     < N_NODES) c0 = (count[base]     + 3) & ~3;
        if (base + 1 < N_NODES) c1 = (count[base + 1] + 3) & ~3;
        if (base + 2 < N_NODES) c2 = (count[base + 2] + 3) & ~3;
        if (base + 3 < N_NODES) c3 = (count[base + 3] + 3) & ~3;
    }
    const int tsum = c0 + c1 + c2 + c3;
    s[tid] = tsum;
    __syncthreads();
    for (int off = 1; off < 256; off <<= 1) {
        int x = (tid >= off) ? s[tid - off] : 0;
        __syncthreads();
        s[tid] += x;
        __syncthreads();
    }
    int o0 = s[tid] - tsum + blockbase;
    int o1 = o0 + c0, o2 = o1 + c1, o3 = o2 + c2;
    if (base + 3 < N_NODES) {
        *(int4*)(offsets + base) = make_int4(o0, o1, o2, o3);
        *(int4*)(cursor  + base) = make_int4(o0, o1, o2, o3);
    } else {
        if (base     < N_NODES) { offsets[base]     = o0; cursor[base]     = o0; }
        if (base + 1 < N_NODES) { offsets[base + 1] = o1; cursor[base + 1] = o1; }
        if (base + 2 < N_NODES) { offsets[base + 2] = o2; cursor[base + 2] = o2; }
        if (base + 3 < N_NODES) { offsets[base + 3] = o3; cursor[base + 3] = o3; }
    }
}

__global__ __launch_bounds__(256) void fill_kernel(
    const int* __restrict__ idx_ji, const int* __restrict__ idx_kj,
    int* __restrict__ cursor, int* __restrict__ edge_kj)
{
    int m = blockIdx.x * 256 + threadIdx.x;
    if (m < M_EDGES) {
        int pos = atomicAdd(&cursor[idx_ji[m]], 1);
        edge_kj[pos] = idx_kj[m];
    }
}

// ---------------------------------------------------------------------------
// Fused attention + normalized aggregation: 16 lanes/node, uint4 gathers,
// 4-EDGE UNROLL (8 row-gathers in flight) with one aligned int4 index load
// per chunk.  Pad entries (never written by fill; 0xAA poison) are handled
// by clamping the index to a real one and zeroing the score.
// ---------------------------------------------------------------------------
__global__ __launch_bounds__(256) void aggregate_kernel(
    const int* __restrict__ edge_kj, const int* __restrict__ offsets,
    const int* __restrict__ count, const ushort* __restrict__ qv16,
    const ushort* __restrict__ k16, ushort* __restrict__ agg16)
{
    const int gid  = blockIdx.x * 256 + threadIdx.x;
    const int node = gid >> 4;
    const int l16  = threadIdx.x & 15;
    if (node >= N_NODES) return;

    const int deg  = count[node];
    const int base = offsets[node];     // multiple of 4

    float kn[8];
    {
        uint4 kp = *(const uint4*)(k16 + (size_t)node * HID + l16 * 8);
        const unsigned int* kw = (const unsigned int*)&kp;
        #pragma unroll
        for (int j = 0; j < 4; ++j) {
            kn[2*j]   = bf16pair_lo(kw[j]);
            kn[2*j+1] = bf16pair_hi(kw[j]);
        }
    }

    float acc[8] = {0.f,0.f,0.f,0.f,0.f,0.f,0.f,0.f};
    float d = 0.f;

    for (int e = 0; e < deg; e += 4) {
        const int rem = deg - e;
        int4 kj4 = *(const int4*)(edge_kj + base + e);   // aligned, pads safe to read
        int kj[4];
        kj[0] = kj4.x;
        kj[1] = (rem > 1) ? kj4.y : kj4.x;
        kj[2] = (rem > 2) ? kj4.z : kj4.x;
        kj[3] = (rem > 3) ? kj4.w : kj4.x;

        uint4 qp[4], vp[4];
        #pragma unroll
        for (int i = 0; i < 4; ++i) {
            const ushort* r = qv16 + (size_t)kj[i] * 256 + l16 * 8;
            qp[i] = *(const uint4*)r;
            vp[i] = *(const uint4*)(r + 128);
        }

        float p[4];
        #pragma unroll
        for (int i = 0; i < 4; ++i) {
            const unsigned int* q = (const unsigned int*)&qp[i];
            float x = 0.f;
            #pragma unroll
            for (int j = 0; j < 4; ++j)
                x += bf16pair_lo(q[j]) * kn[2*j] + bf16pair_hi(q[j]) * kn[2*j+1];
            p[i] = x;
        }
        #pragma unroll
        for (int i = 0; i < 4; ++i) p[i] += __shfl_xor(p[i], 1);

        #pragma unroll
        for (int i = 0; i < 4; ++i) {
            float lr = (p[i] >= 0.f) ? p[i] : 0.2f * p[i];   // leaky_relu(0.2)
            float s  = (i < rem) ? __expf(lr) : 0.f;         // pads contribute 0
            d += s;
            const unsigned int* v = (const unsigned int*)&vp[i];
            #pragma unroll
            for (int j = 0; j < 4; ++j) {
                acc[2*j]   += s * bf16pair_lo(v[j]);
                acc[2*j+1] += s * bf16pair_hi(v[j]);
            }
        }
    }

    const float inv = (deg > 0) ? 1.f / d : 0.f;     // deg==0 -> zeros, not NaN
    uint4 o;
    unsigned int* ow = (unsigned int*)&o;
    #pragma unroll
    for (int j = 0; j < 4; ++j)
        ow[j] = (unsigned int)f32_to_bf16(acc[2*j] * inv)
              | ((unsigned int)f32_to_bf16(acc[2*j+1] * inv) << 16);
    *(uint4*)(agg16 + (size_t)node * HID + l16 * 8) = o;
}

// ---------------------------------------------------------------------------
// Residual MLP via bf16 MFMA, LDS-staged weights (fp32 src, W1 then W2),
// 128 rows/block.  Residual v from interleaved qv (offset 128, stride 256).
// ---------------------------------------------------------------------------
__global__ __launch_bounds__(256) void mlp_mfma_kernel(
    const ushort* __restrict__ agg16, const ushort* __restrict__ qv16,
    const float* __restrict__ W1, const float* __restrict__ b1,
    const float* __restrict__ W2, const float* __restrict__ b2,
    float* __restrict__ out)
{
    __shared__ ushort wlds[16384];    // 32 KB: W1, then W2
    __shared__ ushort h1s[16384];     // 32 KB: 8 tiles x 2048 ushorts (frag order)
    const int tid  = threadIdx.x;
    const int wave = tid >> 6;
    const int lane = tid & 63;
    const int row0 = blockIdx.x * 128 + wave * 32;
    const int lrow = lane & 15;
    const int lk   = (lane >> 4) * 8;
    const int crow = (lane >> 4) * 4;

    // phase 0: load agg A-fragments (2 tiles x 4 ks)
    short8 afrag[2][4];
    bool tvalid[2];
    #pragma unroll
    for (int r = 0; r < 2; ++r) {
        int rr = row0 + r * 16;
        tvalid[r] = (rr < N_NODES);
        const ushort* arow = agg16 + (size_t)((tvalid[r] ? rr : 0) + lrow) * HID + lk;
        #pragma unroll
        for (int ks = 0; ks < 4; ++ks)
            afrag[r][ks] = *(const short8*)(arow + ks * 32);
    }

    stage_w_frag_f32(W1, wlds, tid);
    __syncthreads();

    // phase 1: h1 = relu(agg @ W1.T + b1) -> h1s in A-fragment order
    {
        floatx4 acc[2][8];
        #pragma unroll
        for (int r = 0; r < 2; ++r)
            #pragma unroll
            for (int t = 0; t < 8; ++t) acc[r][t] = (floatx4)(0.f);
        #pragma unroll
        for (int ks = 0; ks < 4; ++ks) {
            short8 B[8];
            #pragma unroll
            for (int t = 0; t < 8; ++t)
                B[t] = *(const short8*)&wlds[(ks * 8 + t) * 512 + lane * 8];
            #pragma unroll
            for (int t = 0; t < 8; ++t) {
                acc[0][t] = __builtin_amdgcn_mfma_f32_16x16x32_bf16(B[t], afrag[0][ks], acc[0][t], 0, 0, 0);
                acc[1][t] = __builtin_amdgcn_mfma_f32_16x16x32_bf16(B[t], afrag[1][ks], acc[1][t], 0, 0, 0);
            }
        }
        #pragma unroll
        for (int r = 0; r < 2; ++r) {
            ushort* tile = &h1s[(wave * 2 + r) * 2048];
            #pragma unroll
            for (int t = 0; t < 8; ++t) {
                float4 bias = *(const float4*)(b1 + t * 16 + crow);
                ushort4 o;
                o.x = f32_to_bf16(fmaxf(acc[r][t][0] + bias.x, 0.f));
                o.y = f32_to_bf16(fmaxf(acc[r][t][1] + bias.y, 0.f));
                o.z = f32_to_bf16(fmaxf(acc[r][t][2] + bias.z, 0.f));
                o.w = f32_to_bf16(fmaxf(acc[r][t][3] + bias.w, 0.f));
                int ks   = t >> 1;
                int quad = (t & 1) * 2 + (crow >> 3);
                int j0   = crow & 4;
                *(ushort4*)(tile + (ks * 64 + quad * 16 + lrow) * 8 + j0) = o;
            }
        }
    }
    __syncthreads();                    // h1 written, wlds reads done
    stage_w_frag_f32(W2, wlds, tid);    // overwrite with W2
    __syncthreads();

    // phase 2: h2 = relu(h1 @ W2.T + b2); out = v + h2
    {
        short8 hfrag[2][4];
        #pragma unroll
        for (int r = 0; r < 2; ++r) {
            const ushort* tile = &h1s[(wave * 2 + r) * 2048];
            #pragma unroll
            for (int ks = 0; ks < 4; ++ks)
                hfrag[r][ks] = *(const short8*)(tile + (ks * 64 + lane) * 8);
        }
        floatx4 acc[2][8];
        #pragma unroll
        for (int r = 0; r < 2; ++r)
            #pragma unroll
            for (int t = 0; t < 8; ++t) acc[r][t] = (floatx4)(0.f);
        #pragma unroll
        for (int ks = 0; ks < 4; ++ks) {
            short8 B[8];
            #pragma unroll
            for (int t = 0; t < 8; ++t)
                B[t] = *(const short8*)&wlds[(ks * 8 + t) * 512 + lane * 8];
            #pragma unroll
            for (int t = 0; t < 8; ++t) {
                acc[0][t] = __builtin_amdgcn_mfma_f32_16x16x32_bf16(B[t], hfrag[0][ks], acc[0][t], 0, 0, 0);
                acc[1][t] = __builtin_amdgcn_mfma_f32_16x16x32_bf16(B[t], hfrag[1][ks], acc[1][t], 0, 0, 0);
            }
        }
        #pragma unroll
        for (int r = 0; r < 2; ++r) {
            if (tvalid[r]) {
                const size_t nrow = (size_t)(row0 + r * 16 + lrow);
                const ushort* vrow = qv16 + nrow * 256 + 128;
                float* orow = out + nrow * HID;
                #pragma unroll
                for (int t = 0; t < 8; ++t) {
                    float4 bias = *(const float4*)(b2 + t * 16 + crow);
                    ushort4 vv = *(const ushort4*)(vrow + t * 16 + crow);
                    float4 o;
                    o.x = bf16_bits_to_f32(vv.x) + fmaxf(acc[r][t][0] + bias.x, 0.f);
                    o.y = bf16_bits_to_f32(vv.y) + fmaxf(acc[r][t][1] + bias.y, 0.f);
                    o.z = bf16_bits_to_f32(vv.z) + fmaxf(acc[r][t][2] + bias.z, 0.f);
                    o.w = bf16_bits_to_f32(vv.w) + fmaxf(acc[r][t][3] + bias.w, 0.f);
                    *(float4*)(orow + t * 16 + crow) = o;
                }
            }
        }
    }
}

extern "C" void kernel_launch(void* const* d_in, const int* in_sizes, int n_in,
                              void* d_out, int out_size, void* d_ws, size_t ws_size,
                              hipStream_t stream) {
    const float* feats  = (const float*)d_in[0];
    const int*   idx_kj = (const int*)d_in[1];
    const int*   idx_ji = (const int*)d_in[2];
    const float* Wv     = (const float*)d_in[3];
    const float* Wq     = (const float*)d_in[4];
    const float* Wk     = (const float*)d_in[5];
    const float* W1     = (const float*)d_in[6];
    const float* b1     = (const float*)d_in[7];
    const float* W2     = (const float*)d_in[8];
    const float* b2     = (const float*)d_in[9];
    float* out = (float*)d_out;

    // workspace layout
    ushort* qv16    = (ushort*)d_ws;                        // [N][256]: q | v
    ushort* k16     = qv16    + (size_t)N_NODES * 256;      // [N][128]
    ushort* agg16   = k16     + (size_t)N_NODES * HID;      // [N][128]
    int* count      = (int*)(agg16 + (size_t)N_NODES * HID);
    int* offsets    = count + N_NODES;                      // padded exclusive prefix
    int* cursor     = offsets + N_NODES;
    int* blocksum   = cursor + N_NODES;
    int* edge_kj    = blocksum + 128;                       // padded: <= M + 3N ints

    qkv_mfma_kernel<<<(N_NODES + 127) / 128, 256, 0, stream>>>(
        feats, Wq, Wk, Wv, qv16, k16, count);

    hist_kernel<<<(M_EDGES + 255) / 256, 256, 0, stream>>>(idx_ji, count);
    scan_blocksum_kernel<<<SCAN_NB, 256, 0, stream>>>(count, blocksum);
    scan_write_kernel<<<SCAN_NB, 256, 0, stream>>>(count, blocksum, offsets, cursor);
    fill_kernel<<<(M_EDGES + 255) / 256, 256, 0, stream>>>(idx_ji, idx_kj, cursor, edge_kj);

    aggregate_kernel<<<((size_t)N_NODES * 16 + 255) / 256, 256, 0, stream>>>(
        edge_kj, offsets, count, qv16, k16, agg16);

    mlp_mfma_kernel<<<(N_NODES + 127) / 128, 256, 0, stream>>>(
        agg16, qv16, W1, b1, W2, b2, out);
}